// Round 1
// baseline (223.447 us; speedup 1.0000x reference)
//
#include <hip/hip_runtime.h>

// out[n,d,b] = unique_weights[indices[n], d] * input_values[n,d,b]
// N=16384, U=1024, D=128, B=16, fp32. Memory-bound elementwise.
// Layout [N,D,B] row-major: flat element e -> n = e/(D*B) = e>>11,
// d = (e/B)%D = (e>>4)&127. Four consecutive b's share one weight scalar,
// so one float4 per thread needs exactly one weight load.

__global__ __launch_bounds__(256) void diagmul_kernel(
    const float4* __restrict__ in,    // N*D*B/4 float4
    const float*  __restrict__ w,     // U*D
    const int*    __restrict__ idx,   // N (int32)
    float4*       __restrict__ out,
    int total_f4)
{
    int i = blockIdx.x * blockDim.x + threadIdx.x;
    if (i >= total_f4) return;

    int e = i << 2;               // flat element index of first lane element
    int n = e >> 11;              // / (D*B) = /2048
    int d = (e >> 4) & 127;       // (/B) % D

    float wv = w[idx[n] * 128 + d];

    float4 v = in[i];
    v.x *= wv; v.y *= wv; v.z *= wv; v.w *= wv;
    out[i] = v;
}

extern "C" void kernel_launch(void* const* d_in, const int* in_sizes, int n_in,
                              void* d_out, int out_size, void* d_ws, size_t ws_size,
                              hipStream_t stream) {
    const float4* in  = (const float4*)d_in[0];   // input_values [N,D,B] fp32
    const float*  w   = (const float*) d_in[1];   // unique_weights [U,D] fp32
    const int*    idx = (const int*)   d_in[2];   // indices [N] int32
    float4*       out = (float4*)      d_out;

    const int total_f4 = out_size / 4;            // 33,554,432 / 4 = 8,388,608
    const int block = 256;
    const int grid  = (total_f4 + block - 1) / block;

    diagmul_kernel<<<grid, block, 0, stream>>>(in, w, idx, out, total_f4);
}